// Round 9
// baseline (240.689 us; speedup 1.0000x reference)
//
#include <hip/hip_runtime.h>
#include <hip/hip_bf16.h>
#include <math.h>

// GATEncoder round 9.
// - gat_gather5: phase B cut from ~11 to ~7 issue slots/edge:
//   (a) interleaved plds (p,s pairs) -> single ds_read_b64;
//   (b) s stored pre-scaled (s<<8 byte offset) -> addr = or(s256, lane*4) + saddr load;
//   (c) guard-free inner loop: phase A always fills all 64 slots (+3 zero pads),
//       tail consumption guarded once per chunk, not per edge.
// - gemm_att: 128-row tile, 512 thr / 8 waves (64KB LDS -> 2 blk/CU = 16 waves),
//   W staged once per 128 rows; dead red[] LDS removed.
// - prep_w folded into part_hist grid (one launch fewer).

#define NEG_SLOPE 0.2f
#define NBLK 256  // partition blocks (P1/P3 grid)

using bf16x8 = __attribute__((ext_vector_type(8))) short;
using f32x4  = __attribute__((ext_vector_type(4))) float;

__device__ inline unsigned short f2bf(float x) {
    union { float f; unsigned int u; } v; v.f = x;
    unsigned int b = v.u + 0x7fffu + ((v.u >> 16) & 1u);  // round-nearest-even
    return (unsigned short)(b >> 16);
}
__device__ inline unsigned int pack2bf(float a, float b) {
    return (unsigned int)f2bf(a) | ((unsigned int)f2bf(b) << 16);
}
__device__ inline float bf_lo(unsigned int u) { return __uint_as_float(u << 16); }
__device__ inline float bf_hi(unsigned int u) { return __uint_as_float(u & 0xffff0000u); }

// exclusive scan of one int per thread across a 256-thread block.
__device__ inline int excl_scan_256(int v, int* scratch4) {
    const int t = threadIdx.x, lane = t & 63, w = t >> 6;
    int incl = v;
#pragma unroll
    for (int o = 1; o < 64; o <<= 1) {
        int u = __shfl_up(incl, o, 64);
        if (lane >= o) incl += u;
    }
    if (lane == 63) scratch4[w] = incl;
    __syncthreads();
    int wb = 0;
#pragma unroll
    for (int k = 0; k < 4; ++k)
        if (k < w) wb += scratch4[k];
    __syncthreads();  // allow scratch reuse
    return wb + incl - v;
}

// ---------------- P1: per-block bucket histogram (+ prep_w piggyback) -------
__global__ __launch_bounds__(256) void part_hist_prep(const int* __restrict__ ei,
                                                      int* __restrict__ hist,
                                                      int E, int NB, int epb,
                                                      const float* __restrict__ W1,
                                                      const float* __restrict__ W2,
                                                      unsigned short* __restrict__ WT1,
                                                      unsigned short* __restrict__ WT2) {
    const int t = threadIdx.x;
    if (blockIdx.x >= NBLK) {  // prep_w: W[k][c] f32 -> WT[c][k] bf16
        __shared__ float Wl[64][132];
        const float* W = (blockIdx.x - NBLK) ? W2 : W1;
        unsigned short* WT = (blockIdx.x - NBLK) ? WT2 : WT1;
        for (int p = 0; p < 2; ++p) {
            if (p) __syncthreads();
            for (int u = t; u < 2048; u += 256) {  // 64 rows x 32 float4
                int row = u >> 5, ch = u & 31;
                float4 v = *(const float4*)(W + (size_t)(p * 64 + row) * 128 + ch * 4);
                Wl[row][ch * 4 + 0] = v.x; Wl[row][ch * 4 + 1] = v.y;
                Wl[row][ch * 4 + 2] = v.z; Wl[row][ch * 4 + 3] = v.w;
            }
            __syncthreads();
            for (int u = t; u < 2048; u += 256) {  // 128 c x 16 kc (4 k each)
                int c = u >> 4, kc = u & 15;
                uint2 o;
                o.x = pack2bf(Wl[kc * 4 + 0][c], Wl[kc * 4 + 1][c]);
                o.y = pack2bf(Wl[kc * 4 + 2][c], Wl[kc * 4 + 3][c]);
                *(uint2*)(WT + (size_t)c * 128 + p * 64 + kc * 4) = o;
            }
        }
        return;
    }
    __shared__ int h[256];
    h[t] = 0;
    __syncthreads();
    const int e0 = blockIdx.x * epb;
    const int e1 = min(e0 + epb, E);
    for (int e = e0 + t; e < e1; e += 256) atomicAdd(&h[ei[E + e] >> 8], 1);
    __syncthreads();
    if (t < NB) hist[t * NBLK + blockIdx.x] = h[t];
}

// ---------------- P2: per-bucket exclusive scan across blocks ----------------
__global__ __launch_bounds__(256) void part_scan(int* __restrict__ hist,
                                                 int* __restrict__ btotal) {
    __shared__ int s4[4];
    const int b = blockIdx.x, t = threadIdx.x;
    const int v = hist[b * NBLK + t];
    const int ex = excl_scan_256(v, s4);
    hist[b * NBLK + t] = ex;
    if (t == 255) btotal[b] = ex + v;
}

// ---------------- P3: partition edges into bucket-grouped part[] -------------
__global__ __launch_bounds__(256) void part_scatter(const int* __restrict__ ei,
                                                    const int* __restrict__ hist,
                                                    const int* __restrict__ btotal,
                                                    unsigned int* __restrict__ part,
                                                    int E, int NB, int epb) {
    __shared__ int s4[4];
    __shared__ int cur[256];
    const int t = threadIdx.x;
    const int tv = (t < NB) ? btotal[t] : 0;
    const int pb = excl_scan_256(tv, s4);
    cur[t] = (t < NB) ? pb + hist[t * NBLK + blockIdx.x] : 0;
    __syncthreads();
    const int e0 = blockIdx.x * epb;
    const int e1 = min(e0 + epb, E);
    for (int e = e0 + t; e < e1; e += 256) {
        const int d = ei[E + e];
        const int s = ei[e];
        const int pos = atomicAdd(&cur[d >> 8], 1);
        part[pos] = (unsigned int)s | ((unsigned int)(d & 255) << 16);
    }
}

// ---------------- P4: per-bucket CSR build (LDS counters) ----------------
__global__ __launch_bounds__(256) void csr_build(const unsigned int* __restrict__ part,
                                                 const int* __restrict__ btotal,
                                                 int* __restrict__ offs,
                                                 int* __restrict__ csr,
                                                 int n, int NB, int E) {
    __shared__ int s4[4];
    __shared__ int cnt[256], curq[256];
    __shared__ int sPB, sPE, sCB;
    const int b = blockIdx.x, t = threadIdx.x;
    const int tv = (t < NB) ? btotal[t] : 0;
    const int nnt = (t < NB) ? max(0, min(256, n - t * 256)) : 0;
    const int e1 = excl_scan_256(tv, s4);        // part base of bucket t
    const int e2 = excl_scan_256(tv + nnt, s4);  // csr base (edges + self-loops)
    if (t == b) { sPB = e1; sPE = e1 + tv; sCB = e2; }
    const int node = b * 256 + t;
    cnt[t] = (node < n) ? 1 : 0;  // self-loop seed
    __syncthreads();
    for (int i = sPB + t; i < sPE; i += 256) atomicAdd(&cnt[(part[i] >> 16) & 255], 1);
    __syncthreads();
    const int c = cnt[t];
    const int loc = excl_scan_256(c, s4);
    curq[t] = loc + ((node < n) ? 1 : 0);
    if (node < n) {
        offs[node] = sCB + loc;
        csr[sCB + loc] = node;  // self-loop first
    }
    if (b == 0 && t == 0) offs[n] = E + n;
    __syncthreads();
    for (int i = sPB + t; i < sPE; i += 256) {
        const unsigned int u = part[i];
        const int pos = atomicAdd(&curq[(u >> 16) & 255], 1);
        csr[sCB + pos] = (int)(u & 0xffffu);
    }
}

// ---------------- MFMA GEMM + fused attention logits ----------------
// block 512 thr = 8 waves, tile 128 rows x 128 cols, K=128 in one LDS stage.
// wave w: rows [w*16, w*16+16). C-frag: col = lane&15, row = (lane>>4)*4 + r.
// LDS XOR-swizzle: byte_in_row ^= ((row&7)<<4). Output Yb permuted:
// storage j = (l&15)*8 + cf  <->  channel col = cf*16 + (l&15).
template <int H, bool IN_F32>
__global__ __launch_bounds__(512) void gemm_att(const float* __restrict__ Xf,
                                                const unsigned short* __restrict__ Xb,
                                                const unsigned short* __restrict__ WTb,
                                                unsigned int* __restrict__ Yb,
                                                const float* __restrict__ att_s,
                                                const float* __restrict__ att_d,
                                                float* __restrict__ as_,
                                                float* __restrict__ ad_, int n) {
    __shared__ unsigned short XL[128 * 128];
    __shared__ unsigned short WL[128 * 128];
    const int tid = threadIdx.x;
    const int r0g = blockIdx.x * 128;
#pragma unroll
    for (int p = 0; p < 4; ++p) {  // stage X tile (swizzled), converting if f32
        int u = tid + 512 * p;     // 128 rows x 16 chunks of 8 ch
        int row = u >> 4, ch = u & 15;
        uint4 v = {0, 0, 0, 0};
        int gr = r0g + row;
        if (gr < n) {
            if constexpr (IN_F32) {
                const float4* xp = (const float4*)(Xf + (size_t)gr * 128 + ch * 8);
                float4 f0 = xp[0], f1 = xp[1];
                v.x = pack2bf(f0.x, f0.y); v.y = pack2bf(f0.z, f0.w);
                v.z = pack2bf(f1.x, f1.y); v.w = pack2bf(f1.z, f1.w);
            } else {
                v = *(const uint4*)(Xb + (size_t)gr * 128 + ch * 8);
            }
        }
        int byte = (ch * 16) ^ ((row & 7) << 4);
        *(uint4*)((char*)XL + row * 256 + byte) = v;
    }
#pragma unroll
    for (int p = 0; p < 4; ++p) {  // stage WT (swizzled)
        int u = tid + 512 * p;     // 128 c x 16 chunks
        int c = u >> 4, ch = u & 15;
        uint4 v = *(const uint4*)(WTb + (size_t)c * 128 + ch * 8);
        int byte = (ch * 16) ^ ((c & 7) << 4);
        *(uint4*)((char*)WL + c * 256 + byte) = v;
    }
    __syncthreads();

    const int w = tid >> 6, lane = tid & 63;
    const int lr = lane & 15, lq = lane >> 4;
    const int swz = (lr & 7) << 4;
    f32x4 acc[8];
#pragma unroll
    for (int cf = 0; cf < 8; ++cf) acc[cf] = (f32x4){0.f, 0.f, 0.f, 0.f};

    const char* XB = (const char*)XL + (w * 16 + lr) * 256;
    const char* WB = (const char*)WL + lr * 256;
#pragma unroll
    for (int k4 = 0; k4 < 4; ++k4) {
        const int off = (k4 * 64 + lq * 16) ^ swz;
        bf16x8 a = *(const bf16x8*)(XB + off);
#pragma unroll
        for (int cf = 0; cf < 8; ++cf) {
            bf16x8 b = *(const bf16x8*)(WB + cf * 4096 + off);
            acc[cf] = __builtin_amdgcn_mfma_f32_16x16x32_bf16(a, b, acc[cf], 0, 0, 0);
        }
    }

    // ---- Yb store (permuted layout) ----
#pragma unroll
    for (int r = 0; r < 4; ++r) {
        int grow = r0g + w * 16 + lq * 4 + r;
        if (grow < n) {
            uint4 o;
            o.x = pack2bf(acc[0][r], acc[1][r]);
            o.y = pack2bf(acc[2][r], acc[3][r]);
            o.z = pack2bf(acc[4][r], acc[5][r]);
            o.w = pack2bf(acc[6][r], acc[7][r]);
            *(uint4*)((unsigned short*)Yb + (size_t)grow * 128 + lr * 8) = o;
        }
    }

    // ---- fused attention logits ----
    if constexpr (H == 4) {
        float pa[4][4], pd[4][4];  // [head][r], compile-time indexed only
#pragma unroll
        for (int h = 0; h < 4; ++h)
#pragma unroll
            for (int r = 0; r < 4; ++r) { pa[h][r] = 0.f; pd[h][r] = 0.f; }
#pragma unroll
        for (int cf = 0; cf < 8; ++cf) {
            const float ws = att_s[cf * 16 + lr];
            const float wd = att_d[cf * 16 + lr];
#pragma unroll
            for (int r = 0; r < 4; ++r) {
                pa[cf >> 1][r] = fmaf(acc[cf][r], ws, pa[cf >> 1][r]);
                pd[cf >> 1][r] = fmaf(acc[cf][r], wd, pd[cf >> 1][r]);
            }
        }
#pragma unroll
        for (int o = 1; o < 16; o <<= 1) {
#pragma unroll
            for (int h = 0; h < 4; ++h)
#pragma unroll
                for (int r = 0; r < 4; ++r) {
                    pa[h][r] += __shfl_xor(pa[h][r], o, 64);
                    pd[h][r] += __shfl_xor(pd[h][r], o, 64);
                }
        }
        const int h = lr & 3, r = lr >> 2;
        float va = 0.f, vd = 0.f;
#pragma unroll
        for (int hh = 0; hh < 4; ++hh)
#pragma unroll
            for (int rr = 0; rr < 4; ++rr)
                if (h == hh && r == rr) { va = pa[hh][rr]; vd = pd[hh][rr]; }
        const int node = r0g + w * 16 + lq * 4 + r;
        if (node < n) {
            as_[(size_t)node * 4 + h] = va;
            ad_[(size_t)node * 4 + h] = vd;
        }
    } else {
        float pa[4], pd[4];
#pragma unroll
        for (int r = 0; r < 4; ++r) { pa[r] = 0.f; pd[r] = 0.f; }
#pragma unroll
        for (int cf = 0; cf < 8; ++cf) {
            const float ws = att_s[cf * 16 + lr];
            const float wd = att_d[cf * 16 + lr];
#pragma unroll
            for (int r = 0; r < 4; ++r) {
                pa[r] = fmaf(acc[cf][r], ws, pa[r]);
                pd[r] = fmaf(acc[cf][r], wd, pd[r]);
            }
        }
#pragma unroll
        for (int o = 1; o < 16; o <<= 1) {
#pragma unroll
            for (int r = 0; r < 4; ++r) {
                pa[r] += __shfl_xor(pa[r], o, 64);
                pd[r] += __shfl_xor(pd[r], o, 64);
            }
        }
        const int r = lr & 3;
        float va = 0.f, vd = 0.f;
#pragma unroll
        for (int rr = 0; rr < 4; ++rr)
            if (r == rr) { va = pa[rr]; vd = pd[rr]; }
        const int node = r0g + w * 16 + lq * 4 + r;
        if (node < n && lr < 8) {
            if (lr < 4) as_[node] = va;
            else        ad_[node] = vd;
        }
    }
}

// ---------------- gather v5: lean broadcast inner loop ----------------
// one wave per dst node; lane owns permuted storage pair {2*lane, 2*lane+1}.
// plds layout (H=4): per edge 8 words (p0,s256,p1,s256,p2,s256,p3,s256);
// lane reads ds_read_b64 at hd*8 bytes. s256 = src<<8 (row byte offset).
// Phase A always fills all 64 slots (+3 zero pad slots) -> guard-free loop.
template <int H, bool DO_ELU, bool OUT_BF16>
__global__ __launch_bounds__(256) void gat_gather5(
    const int* __restrict__ csr, const int* __restrict__ offs,
    const float* __restrict__ as_, const float* __restrict__ ad_,
    const unsigned int* __restrict__ hb,  // permuted bf16 pairs, 64 uints/node
    const float* __restrict__ bias, float* __restrict__ outf,
    unsigned short* __restrict__ outb, int n)
{
    constexpr int PW = (H == 4) ? 8 : 2;  // LDS words per edge
    __shared__ float plds[4][68][PW];     // 64 slots + 3 pad (+1 align)
    const int node = (int)(((size_t)blockIdx.x * blockDim.x + threadIdx.x) >> 6);
    if (node >= n) return;  // whole waves exit; kernel has no block barriers
    const int lane = threadIdx.x & 63;
    const int w = threadIdx.x >> 6;
    const int hd = lane & 3;
    const int lane4 = lane * 4;
    const int col0 = ((2 * lane) & 7) * 16 + (lane >> 2);
    const int col1 = col0 + 16;
    const int start = offs[node];
    const int deg = offs[node + 1] - start;  // >= 1 (self-loop)
    const char* hbp = (const char*)hb;
    // per-lane LDS read base (covers both H cases)
    const char* pb = (const char*)&plds[w][0][0] + ((H == 4) ? hd * 8 : 0);

    // zero the 3 pad slots once (slots 64..66)
    if (lane < 3) {
#pragma unroll
        for (int k = 0; k < PW; ++k) plds[w][64 + lane][k] = 0.f;
    }

    float adx = 0.f, ady = 0.f, adz = 0.f, adw = 0.f;
    if constexpr (H == 4) {
        const float4 adv = *(const float4*)(ad_ + (size_t)node * 4);
        adx = adv.x; ady = adv.y; adz = adv.z; adw = adv.w;
    } else {
        adx = ad_[node];
    }

    float2 acc = {0.f, 0.f};
    float dsx = 0.f, dsy = 0.f, dsz = 0.f, dsw = 0.f;

    for (int base = 0; base < deg; base += 64) {
        const int cnt = min(deg - base, 64);
        // ---- phase A: lane j -> edge j (all 64 slots written) ----
        {
            const bool act = lane < cnt;
            const int s = act ? csr[start + base + lane] : 0;
            const float sf = __int_as_float(s << 8);
            if constexpr (H == 4) {
                const float4 a = ((const float4*)as_)[s];
                float e0 = a.x + adx; e0 = fmaxf(e0, NEG_SLOPE * e0);
                float e1 = a.y + ady; e1 = fmaxf(e1, NEG_SLOPE * e1);
                float e2 = a.z + adz; e2 = fmaxf(e2, NEG_SLOPE * e2);
                float e3 = a.w + adw; e3 = fmaxf(e3, NEG_SLOPE * e3);
                float p0 = act ? __expf(e0) : 0.f;
                float p1 = act ? __expf(e1) : 0.f;
                float p2 = act ? __expf(e2) : 0.f;
                float p3 = act ? __expf(e3) : 0.f;
                dsx += p0; dsy += p1; dsz += p2; dsw += p3;
                float4 w0 = {p0, sf, p1, sf};
                float4 w1 = {p2, sf, p3, sf};
                *(float4*)&plds[w][lane][0] = w0;
                *(float4*)&plds[w][lane][4] = w1;
            } else {
                float e0 = as_[s] + adx; e0 = fmaxf(e0, NEG_SLOPE * e0);
                float p = act ? __expf(e0) : 0.f;
                dsx += p;
                float2 ps = {p, sf};
                *(float2*)&plds[w][lane][0] = ps;
            }
        }
        asm volatile("s_waitcnt lgkmcnt(0)" ::: "memory");
        __builtin_amdgcn_sched_barrier(0);

        // ---- phase B: guard-free depth-3 pipelined broadcast loop ----
        float pA, pB, pC;
        unsigned int hA, hB, hC;
#define PRELB(S, T)                                                              \
    {                                                                            \
        const float2 ps = *(const float2*)(pb + (size_t)(T) * (PW * 4));         \
        p##S = ps.x;                                                             \
        h##S = *(const unsigned int*)(hbp + (__float_as_int(ps.y) | lane4));     \
    }
#define CONSB(S)                                                                 \
    {                                                                            \
        acc.x = fmaf(p##S, bf_lo(h##S), acc.x);                                  \
        acc.y = fmaf(p##S, bf_hi(h##S), acc.y);                                  \
    }
        PRELB(A, 0)
        PRELB(B, 1)
        PRELB(C, 2)
        int t = 0;
        for (; t + 3 <= cnt; t += 3) {
            CONSB(A) PRELB(A, t + 3)
            CONSB(B) PRELB(B, t + 4)
            CONSB(C) PRELB(C, t + 5)
        }
        if (t < cnt)     CONSB(A)
        if (t + 1 < cnt) CONSB(B)
        if (t + 2 < cnt) CONSB(C)
#undef PRELB
#undef CONSB
    }

    // ---- final denom: one butterfly over the lane-local partials ----
#pragma unroll
    for (int o = 1; o < 64; o <<= 1) {
        dsx += __shfl_xor(dsx, o, 64);
        if constexpr (H == 4) {
            dsy += __shfl_xor(dsy, o, 64);
            dsz += __shfl_xor(dsz, o, 64);
            dsw += __shfl_xor(dsw, o, 64);
        }
    }
    float ds;
    if constexpr (H == 4) ds = hd == 0 ? dsx : hd == 1 ? dsy : hd == 2 ? dsz : dsw;
    else                  ds = dsx;

    const float bvx = bias[col0], bvy = bias[col1];
    const float inv = 1.f / (ds + 1e-16f);
    float v0 = acc.x * inv + bvx;
    float v1 = acc.y * inv + bvy;
    if constexpr (DO_ELU) {
        v0 = v0 > 0.f ? v0 : __expf(v0) - 1.f;
        v1 = v1 > 0.f ? v1 : __expf(v1) - 1.f;
    }
    if constexpr (OUT_BF16) {
        unsigned short* o16 = outb + (size_t)node * 128;
        o16[col0] = f2bf(v0);
        o16[col1] = f2bf(v1);
    } else {
        float* o32 = outf + (size_t)node * 128;
        o32[col0] = v0;
        o32[col1] = v1;
    }
}

extern "C" void kernel_launch(void* const* d_in, const int* in_sizes, int n_in,
                              void* d_out, int out_size, void* d_ws, size_t ws_size,
                              hipStream_t stream) {
    const float* x        = (const float*)d_in[0];
    const int*   ei       = (const int*)d_in[1];
    const float* W1       = (const float*)d_in[2];
    const float* att_src1 = (const float*)d_in[3];
    const float* att_dst1 = (const float*)d_in[4];
    const float* b1       = (const float*)d_in[5];
    const float* W2       = (const float*)d_in[6];
    const float* att_src2 = (const float*)d_in[7];
    const float* att_dst2 = (const float*)d_in[8];
    const float* b2       = (const float*)d_in[9];

    const int n  = in_sizes[0] / 128;
    const int E  = in_sizes[1] / 2;
    const int ET = E + n;
    const int NB = (n + 255) >> 8;           // dst buckets (196 for n=50000)
    const int epb = (E + NBLK - 1) / NBLK;   // edges per partition block

    unsigned int*   ws32 = (unsigned int*)d_ws;
    unsigned int*   Yb   = ws32;                                   // [n*64]
    unsigned int*   Bb   = Yb + (size_t)n * 64;                    // [n*64]
    unsigned short* WT1  = (unsigned short*)(Bb + (size_t)n * 64); // [128*128]
    unsigned short* WT2  = WT1 + 128 * 128;                        // [128*128]
    float*          as_  = (float*)(WT2 + 128 * 128);              // [n*4]
    float*          ad_  = as_ + (size_t)n * 4;                    // [n*4]
    int*            offs = (int*)(ad_ + (size_t)n * 4);            // [n+1]
    int*            csr  = offs + n + 1;                           // [ET]
    unsigned int*   part = (unsigned int*)(csr + ET);              // [E]
    int*            hist = (int*)(part + E);                       // [NB*NBLK]
    int*            btot = hist + (size_t)NB * NBLK;               // [NB]

    float* outf = (float*)d_out;

    // ---------------- CSR build (radix partition) + W prep ----------------
    part_hist_prep<<<NBLK + 2, 256, 0, stream>>>(ei, hist, E, NB, epb,
                                                 W1, W2, WT1, WT2);
    part_scan<<<NB, 256, 0, stream>>>(hist, btot);
    part_scatter<<<NBLK, 256, 0, stream>>>(ei, hist, btot, part, E, NB, epb);
    csr_build<<<NB, 256, 0, stream>>>(part, btot, offs, csr, n, NB, E);

    // ---------------- layer 1 ----------------
    gemm_att<4, true><<<(n + 127) / 128, 512, 0, stream>>>(
        x, nullptr, WT1, Yb, att_src1, att_dst1, as_, ad_, n);
    gat_gather5<4, true, true><<<((size_t)n * 64 + 255) / 256, 256, 0, stream>>>(
        csr, offs, as_, ad_, Yb, b1, nullptr, (unsigned short*)Bb, n);

    // ---------------- layer 2 ----------------
    gemm_att<1, false><<<(n + 127) / 128, 512, 0, stream>>>(
        nullptr, (const unsigned short*)Bb, WT2, Yb, att_src2, att_dst2, as_, ad_, n);
    gat_gather5<1, false, false><<<((size_t)n * 64 + 255) / 256, 256, 0, stream>>>(
        csr, offs, as_, ad_, Yb, b2, outf, nullptr, n);
}